// Round 6
// baseline (193.368 us; speedup 1.0000x reference)
//
#include <hip/hip_runtime.h>

#define NG 128

__device__ __forceinline__ int wave_iscan(int v, int lane) {
#pragma unroll
  for (int off = 1; off < 64; off <<= 1) {
    int u = __shfl_up(v, off, 64);
    if (lane >= off) v += u;
  }
  return v;
}

// ---- CSR build ----------------------------------------------------------

__global__ void cnt_kernel(const int* __restrict__ ei, int E, int* __restrict__ cnt) {
  int e = blockIdx.x * blockDim.x + threadIdx.x;
  if (e < E) atomicAdd(&cnt[ei[E + e]], 1);
}

__global__ void bsum_kernel(const int* __restrict__ cnt, int* __restrict__ bsum, int N) {
  __shared__ int wsum[4];
  int tid = threadIdx.x, lane = tid & 63, wid = tid >> 6;
  int i = blockIdx.x * 256 + tid;
  int v = (i < N) ? cnt[i] : 0;
  int inc = wave_iscan(v, lane);
  if (lane == 63) wsum[wid] = inc;
  __syncthreads();
  if (tid == 0) bsum[blockIdx.x] = wsum[0] + wsum[1] + wsum[2] + wsum[3];
}

__global__ void bscan_kernel(int* __restrict__ bsum, int nb) {
  __shared__ int wsum[16];
  int tid = threadIdx.x, lane = tid & 63, wid = tid >> 6;
  int v = (tid < nb) ? bsum[tid] : 0;
  int inc = wave_iscan(v, lane);
  if (lane == 63) wsum[wid] = inc;
  __syncthreads();
  if (tid == 0) {
    int a = 0;
#pragma unroll
    for (int w = 0; w < 16; ++w) { int t = wsum[w]; wsum[w] = a; a += t; }
  }
  __syncthreads();
  if (tid < nb) bsum[tid] = inc - v + wsum[wid];
}

__global__ void rowptr_kernel(const int* __restrict__ cnt, const int* __restrict__ bsum,
                              int* __restrict__ rowptr, int* __restrict__ cursor,
                              float* __restrict__ dis, int N) {
  __shared__ int wsum[4];
  int tid = threadIdx.x, lane = tid & 63, wid = tid >> 6;
  int i = blockIdx.x * 256 + tid;
  int v = (i < N) ? cnt[i] : 0;
  int inc = wave_iscan(v, lane);
  if (lane == 63) wsum[wid] = inc;
  __syncthreads();
  if (tid == 0) {
    int a = bsum[blockIdx.x];
#pragma unroll
    for (int w = 0; w < 4; ++w) { int t = wsum[w]; wsum[w] = a; a += t; }
  }
  __syncthreads();
  if (i < N) {
    int exc = inc - v + wsum[wid];
    rowptr[i] = exc;
    cursor[i] = exc;
    dis[i] = rsqrtf((float)v + 1.0f);  // +1 self loop
  }
}

__global__ void scatter_kernel(const int* __restrict__ ei, int E,
                               int* __restrict__ cursor, const float* __restrict__ dis,
                               int2* __restrict__ epk) {
  int e = blockIdx.x * blockDim.x + threadIdx.x;
  if (e >= E) return;
  int s = ei[e], d = ei[E + e];
  int pos = atomicAdd(&cursor[d], 1);
  epk[pos] = make_int2(s, __float_as_int(dis[s]));
}

// ---- layer 1 fused: wave per node, edge-per-lane gather + W1 matmul -----
// a = dis[d]*( sum_s dis[s]*x[s] + dis[d]*x[d] ); h1[d][j] = relu(b1[j] + a . W1[:,j])
__global__ void l1_kernel(const int* __restrict__ rowptr, const int* __restrict__ cnt,
                          const int2* __restrict__ epk, const float* __restrict__ x,
                          const float* __restrict__ dis, const float* __restrict__ W1,
                          const float* __restrict__ b1, float* __restrict__ h1, int N) {
  int tid = threadIdx.x;
  int lane = tid & 63, wid = tid >> 6;
  int d = __builtin_amdgcn_readfirstlane(blockIdx.x * 4 + wid);
  if (d >= N) return;
  float di = dis[d];
  int p = __builtin_amdgcn_readfirstlane(rowptr[d]);
  int n = __builtin_amdgcn_readfirstlane(cnt[d]);
  float a0 = 0.f, a1 = 0.f, a2 = 0.f, a3 = 0.f;
  for (int k = lane; k < n; k += 64) {
    int2 e = epk[p + k];
    float w = __int_as_float(e.y);
    float4 xv = ((const float4*)x)[e.x];
    a0 = fmaf(w, xv.x, a0); a1 = fmaf(w, xv.y, a1);
    a2 = fmaf(w, xv.z, a2); a3 = fmaf(w, xv.w, a3);
  }
  if (lane == 0) {  // self loop
    float4 xv = ((const float4*)x)[d];
    a0 = fmaf(di, xv.x, a0); a1 = fmaf(di, xv.y, a1);
    a2 = fmaf(di, xv.z, a2); a3 = fmaf(di, xv.w, a3);
  }
#pragma unroll
  for (int off = 1; off < 64; off <<= 1) {
    a0 += __shfl_xor(a0, off, 64);
    a1 += __shfl_xor(a1, off, 64);
    a2 += __shfl_xor(a2, off, 64);
    a3 += __shfl_xor(a3, off, 64);
  }
  a0 *= di; a1 *= di; a2 *= di; a3 *= di;
  float o = b1[lane] + a0 * W1[lane] + a1 * W1[64 + lane] + a2 * W1[128 + lane] + a3 * W1[192 + lane];
  h1[(long)d * 64 + lane] = fmaxf(o, 0.0f);
}

// ---- layer 2 fused: 4x16 wave split gather + matmul + relu + pool -------
// g = lane>>4 owns edge slot, c = lane&15 owns feature quad (float4).
__global__ void l2_kernel(const int* __restrict__ rowptr, const int* __restrict__ cnt,
                          const int2* __restrict__ epk, const float* __restrict__ h1,
                          const float* __restrict__ dis, const float* __restrict__ W2,
                          const float* __restrict__ b2, const int* __restrict__ batch,
                          float* __restrict__ gsum, int N) {
  __shared__ float vbuf[4][64];
  int tid = threadIdx.x;
  int lane = tid & 63, wid = tid >> 6;
  int g = lane >> 4, c = lane & 15;
  int d = __builtin_amdgcn_readfirstlane(blockIdx.x * 4 + wid);
  if (d >= N) return;
  float di = dis[d];
  int p = __builtin_amdgcn_readfirstlane(rowptr[d]);
  int n = __builtin_amdgcn_readfirstlane(cnt[d]);
  float4 acc = make_float4(0.f, 0.f, 0.f, 0.f);
  float4 acc2 = make_float4(0.f, 0.f, 0.f, 0.f);
  if (g == 0) {  // self loop in group 0's partial
    float4 hv = *(const float4*)(h1 + ((long)d << 6) + 4 * c);
    acc.x = di * hv.x; acc.y = di * hv.y; acc.z = di * hv.z; acc.w = di * hv.w;
  }
  int k = 0;
  for (; k + 8 <= n; k += 8) {
    int2 e0 = epk[p + k + g];
    int2 e1 = epk[p + k + 4 + g];
    float4 v0 = *(const float4*)(h1 + ((long)e0.x << 6) + 4 * c);
    float4 v1 = *(const float4*)(h1 + ((long)e1.x << 6) + 4 * c);
    float w0 = __int_as_float(e0.y), w1 = __int_as_float(e1.y);
    acc.x = fmaf(w0, v0.x, acc.x); acc.y = fmaf(w0, v0.y, acc.y);
    acc.z = fmaf(w0, v0.z, acc.z); acc.w = fmaf(w0, v0.w, acc.w);
    acc2.x = fmaf(w1, v1.x, acc2.x); acc2.y = fmaf(w1, v1.y, acc2.y);
    acc2.z = fmaf(w1, v1.z, acc2.z); acc2.w = fmaf(w1, v1.w, acc2.w);
  }
  for (; k < n; k += 4) {  // masked tail (<=2 rounds)
    int idx = k + g;
    int safe = (idx < n) ? idx : (n - 1);
    int2 e = epk[p + safe];
    float w = (idx < n) ? __int_as_float(e.y) : 0.0f;
    float4 v = *(const float4*)(h1 + ((long)e.x << 6) + 4 * c);
    acc.x = fmaf(w, v.x, acc.x); acc.y = fmaf(w, v.y, acc.y);
    acc.z = fmaf(w, v.z, acc.z); acc.w = fmaf(w, v.w, acc.w);
  }
  acc.x += acc2.x; acc.y += acc2.y; acc.z += acc2.z; acc.w += acc2.w;
  // combine the 4 edge groups (lanes differing in bits 4,5)
#pragma unroll
  for (int off = 16; off < 64; off <<= 1) {
    acc.x += __shfl_xor(acc.x, off, 64);
    acc.y += __shfl_xor(acc.y, off, 64);
    acc.z += __shfl_xor(acc.z, off, 64);
    acc.w += __shfl_xor(acc.w, off, 64);
  }
  if (g == 0) {
    float4 v4 = make_float4(di * acc.x, di * acc.y, di * acc.z, di * acc.w);
    *(float4*)(&vbuf[wid][4 * c]) = v4;  // intra-wave, in-order
  }
  float o = b2[lane];
  const float4* vb4 = (const float4*)vbuf[wid];
#pragma unroll
  for (int kk = 0; kk < 16; ++kk) {
    float4 vv = vb4[kk];  // uniform address -> broadcast
    o = fmaf(vv.x, W2[(kk * 4 + 0) * 64 + lane], o);
    o = fmaf(vv.y, W2[(kk * 4 + 1) * 64 + lane], o);
    o = fmaf(vv.z, W2[(kk * 4 + 2) * 64 + lane], o);
    o = fmaf(vv.w, W2[(kk * 4 + 3) * 64 + lane], o);
  }
  o = fmaxf(o, 0.0f);
  atomicAdd(&gsum[batch[d] * 64 + lane], o);
}

// ---- output: mean via binary search on sorted batch ---------------------

__device__ __forceinline__ int lbound(const int* __restrict__ a, int n, int v) {
  int lo = 0, hi = n;
  while (lo < hi) {
    int mid = (lo + hi) >> 1;
    if (a[mid] < v) lo = mid + 1; else hi = mid;
  }
  return lo;
}

__global__ void out_kernel(const float* __restrict__ gsum, const int* __restrict__ batch,
                           int N, float* __restrict__ out) {
  int t = blockIdx.x * blockDim.x + threadIdx.x;
  if (t >= NG * 64) return;
  int g = t >> 6;
  int cnt = lbound(batch, N, g + 1) - lbound(batch, N, g);
  out[t] = gsum[t] / fmaxf((float)cnt, 1.0f);
}

// ---- launch --------------------------------------------------------------

extern "C" void kernel_launch(void* const* d_in, const int* in_sizes, int n_in,
                              void* d_out, int out_size, void* d_ws, size_t ws_size,
                              hipStream_t stream) {
  const float* x = (const float*)d_in[0];
  const int* ei = (const int*)d_in[1];     // [2,E]: src row then dst row
  const int* batch = (const int*)d_in[2];  // sorted graph ids
  const float* W1 = (const float*)d_in[4];
  const float* b1 = (const float*)d_in[5];
  const float* W2 = (const float*)d_in[6];
  const float* b2 = (const float*)d_in[7];

  const int N = in_sizes[0] / 4;
  const int E = in_sizes[1] / 2;
  const int NB = (N + 255) / 256;  // <= 1024

  // ws layout (4B units):
  // [cnt N][gsum 64*NG] <- zeroed each call
  // [rowptr N][cursor N][epk 2E][dis N][h1 64N][bsum NB]
  int* cnt = (int*)d_ws;
  float* gsum = (float*)(cnt + N);
  int* rowptr = (int*)(gsum + 64 * NG);
  int* cursor = rowptr + N;
  int2* epk = (int2*)(cursor + N);  // element count before this is even -> 8B aligned
  float* dis = (float*)(epk + E);
  float* h1 = dis + N;
  int* bsum = (int*)(h1 + (long)64 * N);

  size_t zero_bytes = ((size_t)N + 64 * NG) * 4;
  hipMemsetAsync(d_ws, 0, zero_bytes, stream);

  const int B = 256;
  cnt_kernel<<<(E + B - 1) / B, B, 0, stream>>>(ei, E, cnt);
  bsum_kernel<<<NB, 256, 0, stream>>>(cnt, bsum, N);
  bscan_kernel<<<1, 1024, 0, stream>>>(bsum, NB);
  rowptr_kernel<<<NB, 256, 0, stream>>>(cnt, bsum, rowptr, cursor, dis, N);
  scatter_kernel<<<(E + B - 1) / B, B, 0, stream>>>(ei, E, cursor, dis, epk);
  l1_kernel<<<(N + 3) / 4, 256, 0, stream>>>(rowptr, cnt, epk, x, dis, W1, b1, h1, N);
  l2_kernel<<<(N + 3) / 4, 256, 0, stream>>>(rowptr, cnt, epk, h1, dis, W2, b2, batch, gsum, N);
  out_kernel<<<(NG * 64 + B - 1) / B, B, 0, stream>>>(gsum, batch, N, (float*)d_out);
}

// Round 7
// 184.455 us; speedup vs baseline: 1.0483x; 1.0483x over previous
//
#include <hip/hip_runtime.h>

#define NG 128

__device__ __forceinline__ int wave_iscan(int v, int lane) {
#pragma unroll
  for (int off = 1; off < 64; off <<= 1) {
    int u = __shfl_up(v, off, 64);
    if (lane >= off) v += u;
  }
  return v;
}

// ---- CSR build ----------------------------------------------------------

__global__ void cnt_kernel(const int* __restrict__ ei, int E, int* __restrict__ cnt) {
  int e = blockIdx.x * blockDim.x + threadIdx.x;
  if (e < E) atomicAdd(&cnt[ei[E + e]], 1);
}

__global__ void bsum_kernel(const int* __restrict__ cnt, int* __restrict__ bsum, int N) {
  __shared__ int wsum[4];
  int tid = threadIdx.x, lane = tid & 63, wid = tid >> 6;
  int i = blockIdx.x * 256 + tid;
  int v = (i < N) ? cnt[i] : 0;
  int inc = wave_iscan(v, lane);
  if (lane == 63) wsum[wid] = inc;
  __syncthreads();
  if (tid == 0) bsum[blockIdx.x] = wsum[0] + wsum[1] + wsum[2] + wsum[3];
}

__global__ void bscan_kernel(int* __restrict__ bsum, int nb) {
  __shared__ int wsum[16];
  int tid = threadIdx.x, lane = tid & 63, wid = tid >> 6;
  int v = (tid < nb) ? bsum[tid] : 0;
  int inc = wave_iscan(v, lane);
  if (lane == 63) wsum[wid] = inc;
  __syncthreads();
  if (tid == 0) {
    int a = 0;
#pragma unroll
    for (int w = 0; w < 16; ++w) { int t = wsum[w]; wsum[w] = a; a += t; }
  }
  __syncthreads();
  if (tid < nb) bsum[tid] = inc - v + wsum[wid];
}

__global__ void rowptr_kernel(const int* __restrict__ cnt, const int* __restrict__ bsum,
                              int* __restrict__ rowptr, int* __restrict__ cursor,
                              float* __restrict__ dis, int N) {
  __shared__ int wsum[4];
  int tid = threadIdx.x, lane = tid & 63, wid = tid >> 6;
  int i = blockIdx.x * 256 + tid;
  int v = (i < N) ? cnt[i] : 0;
  int inc = wave_iscan(v, lane);
  if (lane == 63) wsum[wid] = inc;
  __syncthreads();
  if (tid == 0) {
    int a = bsum[blockIdx.x];
#pragma unroll
    for (int w = 0; w < 4; ++w) { int t = wsum[w]; wsum[w] = a; a += t; }
  }
  __syncthreads();
  if (i < N) {
    int exc = inc - v + wsum[wid];
    rowptr[i] = exc;
    cursor[i] = exc;
    dis[i] = rsqrtf((float)v + 1.0f);  // +1 self loop
  }
}

__global__ void scatter_kernel(const int* __restrict__ ei, int E,
                               int* __restrict__ cursor, const float* __restrict__ dis,
                               int2* __restrict__ epk) {
  int e = blockIdx.x * blockDim.x + threadIdx.x;
  if (e >= E) return;
  int s = ei[e], d = ei[E + e];
  int pos = atomicAdd(&cursor[d], 1);
  epk[pos] = make_int2(s, __float_as_int(dis[s]));
}

// ---- layer 1 fused: wave per node, edge-per-lane gather + W1 matmul -----
__global__ void l1_kernel(const int* __restrict__ rowptr, const int* __restrict__ cnt,
                          const int2* __restrict__ epk, const float* __restrict__ x,
                          const float* __restrict__ dis, const float* __restrict__ W1,
                          const float* __restrict__ b1, float* __restrict__ h1, int N) {
  int tid = threadIdx.x;
  int lane = tid & 63, wid = tid >> 6;
  int d = __builtin_amdgcn_readfirstlane(blockIdx.x * 4 + wid);
  if (d >= N) return;
  float di = dis[d];
  int p = __builtin_amdgcn_readfirstlane(rowptr[d]);
  int n = __builtin_amdgcn_readfirstlane(cnt[d]);
  float a0 = 0.f, a1 = 0.f, a2 = 0.f, a3 = 0.f;
  for (int k = lane; k < n; k += 64) {
    int2 e = epk[p + k];
    float w = __int_as_float(e.y);
    float4 xv = ((const float4*)x)[e.x];
    a0 = fmaf(w, xv.x, a0); a1 = fmaf(w, xv.y, a1);
    a2 = fmaf(w, xv.z, a2); a3 = fmaf(w, xv.w, a3);
  }
  if (lane == 0) {  // self loop
    float4 xv = ((const float4*)x)[d];
    a0 = fmaf(di, xv.x, a0); a1 = fmaf(di, xv.y, a1);
    a2 = fmaf(di, xv.z, a2); a3 = fmaf(di, xv.w, a3);
  }
#pragma unroll
  for (int off = 1; off < 64; off <<= 1) {
    a0 += __shfl_xor(a0, off, 64);
    a1 += __shfl_xor(a1, off, 64);
    a2 += __shfl_xor(a2, off, 64);
    a3 += __shfl_xor(a3, off, 64);
  }
  a0 *= di; a1 *= di; a2 *= di; a3 *= di;
  float o = b1[lane] + a0 * W1[lane] + a1 * W1[64 + lane] + a2 * W1[128 + lane] + a3 * W1[192 + lane];
  h1[(long)d * 64 + lane] = fmaxf(o, 0.0f);
}

// ---- layer 2 fused: gather + matmul + relu + block-combined pool --------
// 16 waves/block = 16 consecutive nodes. Per-wave: R5-style uniform-epk
// gather + LDS W2 broadcast matmul. Pool: rows staged in LDS, wave 0
// run-combines (batch sorted) -> ~1 atomic row per block instead of 16.
__global__ void __launch_bounds__(1024, 2)
l2_kernel(const int* __restrict__ rowptr, const int* __restrict__ cnt,
          const int2* __restrict__ epk, const float* __restrict__ h1,
          const float* __restrict__ dis, const float* __restrict__ W2,
          const float* __restrict__ b2, const int* __restrict__ batch,
          float* __restrict__ gsum, int N) {
  __shared__ float vbuf[16][64];
  __shared__ float obuf[16][64];
  __shared__ int gbuf[16];
  int tid = threadIdx.x;
  int lane = tid & 63, wid = tid >> 6;
  int d0 = blockIdx.x * 16 + wid;
  bool valid = d0 < N;
  int d = __builtin_amdgcn_readfirstlane(valid ? d0 : N - 1);
  float di = dis[d];
  float acc0 = di * h1[(long)d * 64 + lane];  // self loop
  float acc1 = 0.f, acc2 = 0.f, acc3 = 0.f;
  int p = __builtin_amdgcn_readfirstlane(rowptr[d]);
  int n = __builtin_amdgcn_readfirstlane(cnt[d]);
  int k = 0;
  for (; k + 4 <= n; k += 4) {
    int2 e0 = epk[p + k], e1 = epk[p + k + 1], e2 = epk[p + k + 2], e3 = epk[p + k + 3];
    float v0 = h1[(long)e0.x * 64 + lane];
    float v1 = h1[(long)e1.x * 64 + lane];
    float v2 = h1[(long)e2.x * 64 + lane];
    float v3 = h1[(long)e3.x * 64 + lane];
    acc0 = fmaf(__int_as_float(e0.y), v0, acc0);
    acc1 = fmaf(__int_as_float(e1.y), v1, acc1);
    acc2 = fmaf(__int_as_float(e2.y), v2, acc2);
    acc3 = fmaf(__int_as_float(e3.y), v3, acc3);
  }
  for (; k < n; ++k) {
    int2 e = epk[p + k];
    acc0 = fmaf(__int_as_float(e.y), h1[(long)e.x * 64 + lane], acc0);
  }
  float v = di * ((acc0 + acc1) + (acc2 + acc3));
  vbuf[wid][lane] = v;  // intra-wave, in-order
  float o = b2[lane];
  const float4* vb4 = (const float4*)vbuf[wid];
#pragma unroll
  for (int kk = 0; kk < 16; ++kk) {
    float4 vv = vb4[kk];  // uniform address -> broadcast read
    o = fmaf(vv.x, W2[(kk * 4 + 0) * 64 + lane], o);
    o = fmaf(vv.y, W2[(kk * 4 + 1) * 64 + lane], o);
    o = fmaf(vv.z, W2[(kk * 4 + 2) * 64 + lane], o);
    o = fmaf(vv.w, W2[(kk * 4 + 3) * 64 + lane], o);
  }
  obuf[wid][lane] = fmaxf(o, 0.0f);
  if (lane == 0) gbuf[wid] = valid ? batch[d] : -1;
  __syncthreads();
  if (wid == 0) {
    float s = 0.0f;
    int cur = gbuf[0];
#pragma unroll
    for (int r = 0; r < 16; ++r) {
      int g = gbuf[r];
      if (g != cur) {
        if (cur >= 0) atomicAdd(&gsum[cur * 64 + lane], s);
        s = 0.0f;
        cur = g;
      }
      if (g >= 0) s += obuf[r][lane];
    }
    if (cur >= 0) atomicAdd(&gsum[cur * 64 + lane], s);
  }
}

// ---- output: mean via binary search on sorted batch ---------------------

__device__ __forceinline__ int lbound(const int* __restrict__ a, int n, int v) {
  int lo = 0, hi = n;
  while (lo < hi) {
    int mid = (lo + hi) >> 1;
    if (a[mid] < v) lo = mid + 1; else hi = mid;
  }
  return lo;
}

__global__ void out_kernel(const float* __restrict__ gsum, const int* __restrict__ batch,
                           int N, float* __restrict__ out) {
  int t = blockIdx.x * blockDim.x + threadIdx.x;
  if (t >= NG * 64) return;
  int g = t >> 6;
  int cnt = lbound(batch, N, g + 1) - lbound(batch, N, g);
  out[t] = gsum[t] / fmaxf((float)cnt, 1.0f);
}

// ---- launch --------------------------------------------------------------

extern "C" void kernel_launch(void* const* d_in, const int* in_sizes, int n_in,
                              void* d_out, int out_size, void* d_ws, size_t ws_size,
                              hipStream_t stream) {
  const float* x = (const float*)d_in[0];
  const int* ei = (const int*)d_in[1];     // [2,E]: src row then dst row
  const int* batch = (const int*)d_in[2];  // sorted graph ids
  const float* W1 = (const float*)d_in[4];
  const float* b1 = (const float*)d_in[5];
  const float* W2 = (const float*)d_in[6];
  const float* b2 = (const float*)d_in[7];

  const int N = in_sizes[0] / 4;
  const int E = in_sizes[1] / 2;
  const int NB = (N + 255) / 256;  // <= 1024

  // ws layout (4B units):
  // [cnt N][gsum 64*NG] <- zeroed each call
  // [rowptr N][cursor N][epk 2E][dis N][h1 64N][bsum NB]
  int* cnt = (int*)d_ws;
  float* gsum = (float*)(cnt + N);
  int* rowptr = (int*)(gsum + 64 * NG);
  int* cursor = rowptr + N;
  int2* epk = (int2*)(cursor + N);  // element count before this is even -> 8B aligned
  float* dis = (float*)(epk + E);
  float* h1 = dis + N;
  int* bsum = (int*)(h1 + (long)64 * N);

  size_t zero_bytes = ((size_t)N + 64 * NG) * 4;
  hipMemsetAsync(d_ws, 0, zero_bytes, stream);

  const int B = 256;
  cnt_kernel<<<(E + B - 1) / B, B, 0, stream>>>(ei, E, cnt);
  bsum_kernel<<<NB, 256, 0, stream>>>(cnt, bsum, N);
  bscan_kernel<<<1, 1024, 0, stream>>>(bsum, NB);
  rowptr_kernel<<<NB, 256, 0, stream>>>(cnt, bsum, rowptr, cursor, dis, N);
  scatter_kernel<<<(E + B - 1) / B, B, 0, stream>>>(ei, E, cursor, dis, epk);
  l1_kernel<<<(N + 3) / 4, 256, 0, stream>>>(rowptr, cnt, epk, x, dis, W1, b1, h1, N);
  l2_kernel<<<(N + 15) / 16, 1024, 0, stream>>>(rowptr, cnt, epk, h1, dis, W2, b2, batch, gsum, N);
  out_kernel<<<(NG * 64 + B - 1) / B, B, 0, stream>>>(gsum, batch, N, (float*)d_out);
}

// Round 8
// 173.905 us; speedup vs baseline: 1.1119x; 1.0607x over previous
//
#include <hip/hip_runtime.h>

#define NG 128

__device__ __forceinline__ int wave_iscan(int v, int lane) {
#pragma unroll
  for (int off = 1; off < 64; off <<= 1) {
    int u = __shfl_up(v, off, 64);
    if (lane >= off) v += u;
  }
  return v;
}

// ---- CSR build ----------------------------------------------------------

__global__ void cnt_kernel(const int* __restrict__ ei, int E, int* __restrict__ cnt) {
  int e = blockIdx.x * blockDim.x + threadIdx.x;
  if (e < E) atomicAdd(&cnt[ei[E + e]], 1);
}

__global__ void bsum_kernel(const int* __restrict__ cnt, int* __restrict__ bsum, int N) {
  __shared__ int wsum[4];
  int tid = threadIdx.x, lane = tid & 63, wid = tid >> 6;
  int i = blockIdx.x * 256 + tid;
  int v = (i < N) ? cnt[i] : 0;
  int inc = wave_iscan(v, lane);
  if (lane == 63) wsum[wid] = inc;
  __syncthreads();
  if (tid == 0) bsum[blockIdx.x] = wsum[0] + wsum[1] + wsum[2] + wsum[3];
}

__global__ void bscan_kernel(int* __restrict__ bsum, int nb) {
  __shared__ int wsum[16];
  int tid = threadIdx.x, lane = tid & 63, wid = tid >> 6;
  int v = (tid < nb) ? bsum[tid] : 0;
  int inc = wave_iscan(v, lane);
  if (lane == 63) wsum[wid] = inc;
  __syncthreads();
  if (tid == 0) {
    int a = 0;
#pragma unroll
    for (int w = 0; w < 16; ++w) { int t = wsum[w]; wsum[w] = a; a += t; }
  }
  __syncthreads();
  if (tid < nb) bsum[tid] = inc - v + wsum[wid];
}

// rowptr = exclusive scan; cursor = copy; dis = rsqrt(deg+1); xs = dis*x
__global__ void rowptr_kernel(const int* __restrict__ cnt, const int* __restrict__ bsum,
                              int* __restrict__ rowptr, int* __restrict__ cursor,
                              float* __restrict__ dis, const float* __restrict__ x,
                              float* __restrict__ xs, int N) {
  __shared__ int wsum[4];
  int tid = threadIdx.x, lane = tid & 63, wid = tid >> 6;
  int i = blockIdx.x * 256 + tid;
  int v = (i < N) ? cnt[i] : 0;
  int inc = wave_iscan(v, lane);
  if (lane == 63) wsum[wid] = inc;
  __syncthreads();
  if (tid == 0) {
    int a = bsum[blockIdx.x];
#pragma unroll
    for (int w = 0; w < 4; ++w) { int t = wsum[w]; wsum[w] = a; a += t; }
  }
  __syncthreads();
  if (i < N) {
    int exc = inc - v + wsum[wid];
    rowptr[i] = exc;
    cursor[i] = exc;
    float di = rsqrtf((float)v + 1.0f);  // +1 self loop
    dis[i] = di;
    float4 xv = ((const float4*)x)[i];
    ((float4*)xs)[i] = make_float4(di * xv.x, di * xv.y, di * xv.z, di * xv.w);
  }
}

// counting-sort scatter: esrc[pos] = src bucketed by dst (4B writes only)
__global__ void scatter_kernel(const int* __restrict__ ei, int E,
                               int* __restrict__ cursor, int* __restrict__ esrc) {
  int e = blockIdx.x * blockDim.x + threadIdx.x;
  if (e >= E) return;
  int s = ei[e], d = ei[E + e];
  int pos = atomicAdd(&cursor[d], 1);
  esrc[pos] = s;
}

// ---- layer 1 fused: wave per node; gather xs; h1p = dis*relu(aggr@W1+b1) --
__global__ void l1_kernel(const int* __restrict__ rowptr, const int* __restrict__ cnt,
                          const int* __restrict__ esrc, const float* __restrict__ xs,
                          const float* __restrict__ x, const float* __restrict__ dis,
                          const float* __restrict__ W1, const float* __restrict__ b1,
                          float* __restrict__ h1p, int N) {
  int tid = threadIdx.x;
  int lane = tid & 63, wid = tid >> 6;
  int d = __builtin_amdgcn_readfirstlane(blockIdx.x * 4 + wid);
  if (d >= N) return;
  float di = dis[d];
  int p = __builtin_amdgcn_readfirstlane(rowptr[d]);
  int n = __builtin_amdgcn_readfirstlane(cnt[d]);
  float a0 = 0.f, a1 = 0.f, a2 = 0.f, a3 = 0.f;
  for (int k = lane; k < n; k += 64) {
    int e = esrc[p + k];
    float4 v = ((const float4*)xs)[e];
    a0 += v.x; a1 += v.y; a2 += v.z; a3 += v.w;
  }
  if (lane == 0) {  // self loop: + di*x[d]
    float4 xv = ((const float4*)x)[d];
    a0 = fmaf(di, xv.x, a0); a1 = fmaf(di, xv.y, a1);
    a2 = fmaf(di, xv.z, a2); a3 = fmaf(di, xv.w, a3);
  }
#pragma unroll
  for (int off = 1; off < 64; off <<= 1) {
    a0 += __shfl_xor(a0, off, 64);
    a1 += __shfl_xor(a1, off, 64);
    a2 += __shfl_xor(a2, off, 64);
    a3 += __shfl_xor(a3, off, 64);
  }
  a0 *= di; a1 *= di; a2 *= di; a3 *= di;
  float o = b1[lane] + a0 * W1[lane] + a1 * W1[64 + lane] + a2 * W1[128 + lane] + a3 * W1[192 + lane];
  h1p[(long)d * 64 + lane] = di * fmaxf(o, 0.0f);
}

// ---- layer 2: weightless gather (unroll-8) + matmul + relu + pooled -----
// 8 waves/block = 8 consecutive nodes; run-combined pool (batch sorted).
__global__ void __launch_bounds__(512)
l2_kernel(const int* __restrict__ rowptr, const int* __restrict__ cnt,
          const int* __restrict__ esrc, const float* __restrict__ h1p,
          const float* __restrict__ dis, const float* __restrict__ W2,
          const float* __restrict__ b2, const int* __restrict__ batch,
          float* __restrict__ gsum, int N) {
  __shared__ float vbuf[8][64];
  __shared__ float obuf[8][64];
  __shared__ int gbuf[8];
  int tid = threadIdx.x;
  int lane = tid & 63, wid = tid >> 6;
  int d0 = blockIdx.x * 8 + wid;
  bool valid = d0 < N;
  int d = __builtin_amdgcn_readfirstlane(valid ? d0 : N - 1);
  float di = dis[d];
  float acc0 = h1p[(long)d * 64 + lane];  // self loop (h1p already has dis factor)
  float acc1 = 0.f, acc2 = 0.f, acc3 = 0.f;
  float acc4 = 0.f, acc5 = 0.f, acc6 = 0.f, acc7 = 0.f;
  int p = __builtin_amdgcn_readfirstlane(rowptr[d]);
  int n = __builtin_amdgcn_readfirstlane(cnt[d]);
  int k = 0;
  for (; k + 8 <= n; k += 8) {
    int e0 = esrc[p + k + 0], e1 = esrc[p + k + 1];
    int e2 = esrc[p + k + 2], e3 = esrc[p + k + 3];
    int e4 = esrc[p + k + 4], e5 = esrc[p + k + 5];
    int e6 = esrc[p + k + 6], e7 = esrc[p + k + 7];
    acc0 += h1p[(long)e0 * 64 + lane];
    acc1 += h1p[(long)e1 * 64 + lane];
    acc2 += h1p[(long)e2 * 64 + lane];
    acc3 += h1p[(long)e3 * 64 + lane];
    acc4 += h1p[(long)e4 * 64 + lane];
    acc5 += h1p[(long)e5 * 64 + lane];
    acc6 += h1p[(long)e6 * 64 + lane];
    acc7 += h1p[(long)e7 * 64 + lane];
  }
  if (k < n) {  // masked tail, <=7 edges, still independent loads
#pragma unroll
    for (int i = 0; i < 7; ++i) {
      int idx = k + i;
      int safe = (idx < n) ? idx : (n - 1);
      float m = (idx < n) ? 1.0f : 0.0f;
      int e = esrc[p + safe];
      float v = h1p[(long)e * 64 + lane];
      switch (i & 3) {  // spread across accumulators
        case 0: acc1 = fmaf(m, v, acc1); break;
        case 1: acc2 = fmaf(m, v, acc2); break;
        case 2: acc3 = fmaf(m, v, acc3); break;
        case 3: acc4 = fmaf(m, v, acc4); break;
      }
    }
  }
  float v = di * (((acc0 + acc1) + (acc2 + acc3)) + ((acc4 + acc5) + (acc6 + acc7)));
  vbuf[wid][lane] = v;  // intra-wave, in-order
  float o = b2[lane];
  const float4* vb4 = (const float4*)vbuf[wid];
#pragma unroll
  for (int kk = 0; kk < 16; ++kk) {
    float4 vv = vb4[kk];  // uniform address -> broadcast read
    o = fmaf(vv.x, W2[(kk * 4 + 0) * 64 + lane], o);
    o = fmaf(vv.y, W2[(kk * 4 + 1) * 64 + lane], o);
    o = fmaf(vv.z, W2[(kk * 4 + 2) * 64 + lane], o);
    o = fmaf(vv.w, W2[(kk * 4 + 3) * 64 + lane], o);
  }
  obuf[wid][lane] = fmaxf(o, 0.0f);
  if (lane == 0) gbuf[wid] = valid ? batch[d] : -1;
  __syncthreads();
  if (wid == 0) {
    float s = 0.0f;
    int cur = gbuf[0];
#pragma unroll
    for (int r = 0; r < 8; ++r) {
      int g = gbuf[r];
      if (g != cur) {
        if (cur >= 0) atomicAdd(&gsum[cur * 64 + lane], s);
        s = 0.0f;
        cur = g;
      }
      if (g >= 0) s += obuf[r][lane];
    }
    if (cur >= 0) atomicAdd(&gsum[cur * 64 + lane], s);
  }
}

// ---- output: mean via binary search on sorted batch ---------------------

__device__ __forceinline__ int lbound(const int* __restrict__ a, int n, int v) {
  int lo = 0, hi = n;
  while (lo < hi) {
    int mid = (lo + hi) >> 1;
    if (a[mid] < v) lo = mid + 1; else hi = mid;
  }
  return lo;
}

__global__ void out_kernel(const float* __restrict__ gsum, const int* __restrict__ batch,
                           int N, float* __restrict__ out) {
  int t = blockIdx.x * blockDim.x + threadIdx.x;
  if (t >= NG * 64) return;
  int g = t >> 6;
  int cnt = lbound(batch, N, g + 1) - lbound(batch, N, g);
  out[t] = gsum[t] / fmaxf((float)cnt, 1.0f);
}

// ---- launch --------------------------------------------------------------

extern "C" void kernel_launch(void* const* d_in, const int* in_sizes, int n_in,
                              void* d_out, int out_size, void* d_ws, size_t ws_size,
                              hipStream_t stream) {
  const float* x = (const float*)d_in[0];
  const int* ei = (const int*)d_in[1];     // [2,E]: src row then dst row
  const int* batch = (const int*)d_in[2];  // sorted graph ids
  const float* W1 = (const float*)d_in[4];
  const float* b1 = (const float*)d_in[5];
  const float* W2 = (const float*)d_in[6];
  const float* b2 = (const float*)d_in[7];

  const int N = in_sizes[0] / 4;
  const int E = in_sizes[1] / 2;
  const int NB = (N + 255) / 256;  // <= 1024

  // ws layout (4B units):
  // [cnt N][gsum 64*NG] <- zeroed each call
  // [xs 4N (16B-aligned)][rowptr N][cursor N][esrc E][dis N][h1p 64N][bsum NB]
  int* cnt = (int*)d_ws;
  float* gsum = (float*)(cnt + N);
  float* xs = gsum + 64 * NG;       // offset (N + 8192) floats -> 16B aligned for N%4==0
  int* rowptr = (int*)(xs + (long)4 * N);
  int* cursor = rowptr + N;
  int* esrc = cursor + N;
  float* dis = (float*)(esrc + E);
  float* h1p = dis + N;
  int* bsum = (int*)(h1p + (long)64 * N);

  size_t zero_bytes = ((size_t)N + 64 * NG) * 4;
  hipMemsetAsync(d_ws, 0, zero_bytes, stream);

  const int B = 256;
  cnt_kernel<<<(E + B - 1) / B, B, 0, stream>>>(ei, E, cnt);
  bsum_kernel<<<NB, 256, 0, stream>>>(cnt, bsum, N);
  bscan_kernel<<<1, 1024, 0, stream>>>(bsum, NB);
  rowptr_kernel<<<NB, 256, 0, stream>>>(cnt, bsum, rowptr, cursor, dis, x, xs, N);
  scatter_kernel<<<(E + B - 1) / B, B, 0, stream>>>(ei, E, cursor, esrc);
  l1_kernel<<<(N + 3) / 4, 256, 0, stream>>>(rowptr, cnt, esrc, xs, x, dis, W1, b1, h1p, N);
  l2_kernel<<<(N + 7) / 8, 512, 0, stream>>>(rowptr, cnt, esrc, h1p, dis, W2, b2, batch, gsum, N);
  out_kernel<<<(NG * 64 + B - 1) / B, B, 0, stream>>>(gsum, batch, N, (float*)d_out);
}

// Round 9
// 170.510 us; speedup vs baseline: 1.1341x; 1.0199x over previous
//
#include <hip/hip_runtime.h>

#define NG 128

__device__ __forceinline__ int wave_iscan(int v, int lane) {
#pragma unroll
  for (int off = 1; off < 64; off <<= 1) {
    int u = __shfl_up(v, off, 64);
    if (lane >= off) v += u;
  }
  return v;
}

// ---- degree + rowptr -----------------------------------------------------

__global__ void cnt_kernel(const int* __restrict__ ei, int E, int* __restrict__ cnt) {
  int e = blockIdx.x * blockDim.x + threadIdx.x;
  if (e < E) atomicAdd(&cnt[ei[E + e]], 1);
}

__global__ void bsum_kernel(const int* __restrict__ src, int* __restrict__ bsum, int M) {
  __shared__ int wsum[4];
  int tid = threadIdx.x, lane = tid & 63, wid = tid >> 6;
  int i = blockIdx.x * 256 + tid;
  int v = (i < M) ? src[i] : 0;
  int inc = wave_iscan(v, lane);
  if (lane == 63) wsum[wid] = inc;
  __syncthreads();
  if (tid == 0) bsum[blockIdx.x] = wsum[0] + wsum[1] + wsum[2] + wsum[3];
}

__global__ void bscan_kernel(int* __restrict__ bsum, int nb) {
  __shared__ int wsum[16];
  int tid = threadIdx.x, lane = tid & 63, wid = tid >> 6;
  int v = (tid < nb) ? bsum[tid] : 0;
  int inc = wave_iscan(v, lane);
  if (lane == 63) wsum[wid] = inc;
  __syncthreads();
  if (tid == 0) {
    int a = 0;
#pragma unroll
    for (int w = 0; w < 16; ++w) { int t = wsum[w]; wsum[w] = a; a += t; }
  }
  __syncthreads();
  if (tid < nb) bsum[tid] = inc - v + wsum[wid];
}

// rowptr = exclusive scan of cnt; dis = rsqrt(deg+1); xs = dis*x
__global__ void rowptr_kernel(const int* __restrict__ cnt, const int* __restrict__ bsum,
                              int* __restrict__ rowptr, float* __restrict__ dis,
                              const float* __restrict__ x, float* __restrict__ xs, int N) {
  __shared__ int wsum[4];
  int tid = threadIdx.x, lane = tid & 63, wid = tid >> 6;
  int i = blockIdx.x * 256 + tid;
  int v = (i < N) ? cnt[i] : 0;
  int inc = wave_iscan(v, lane);
  if (lane == 63) wsum[wid] = inc;
  __syncthreads();
  if (tid == 0) {
    int a = bsum[blockIdx.x];
#pragma unroll
    for (int w = 0; w < 4; ++w) { int t = wsum[w]; wsum[w] = a; a += t; }
  }
  __syncthreads();
  if (i < N) {
    rowptr[i] = inc - v + wsum[wid];
    float di = rsqrtf((float)v + 1.0f);  // +1 self loop
    dis[i] = di;
    float4 xv = ((const float4*)x)[i];
    ((float4*)xs)[i] = make_float4(di * xv.x, di * xv.y, di * xv.z, di * xv.w);
  }
}

// generic exclusive-scan add-back, in-place (for the off array)
__global__ void offadd_kernel(int* __restrict__ off, const int* __restrict__ bsum, int M) {
  __shared__ int wsum[4];
  int tid = threadIdx.x, lane = tid & 63, wid = tid >> 6;
  int i = blockIdx.x * 256 + tid;
  int v = (i < M) ? off[i] : 0;
  int inc = wave_iscan(v, lane);
  if (lane == 63) wsum[wid] = inc;
  __syncthreads();
  if (tid == 0) {
    int a = bsum[blockIdx.x];
#pragma unroll
    for (int w = 0; w < 4; ++w) { int t = wsum[w]; wsum[w] = a; a += t; }
  }
  __syncthreads();
  if (i < M) off[i] = inc - v + wsum[wid];
}

// ---- bucketed edge reorder (bucket = dst >> 8) --------------------------

// per-chunk bucket histogram: off[q*nblkE + blk] = count
__global__ void hist_kernel(const int* __restrict__ ei, int E, int nblkE, int K,
                            int* __restrict__ off) {
  __shared__ int lh[256];
  int tid = threadIdx.x, blk = blockIdx.x;
  lh[tid] = 0;
  __syncthreads();
  int e0 = blk * 8192;
  for (int i = tid; i < 8192; i += 256) {
    int e = e0 + i;
    if (e < E) atomicAdd(&lh[ei[E + e] >> 8], 1);
  }
  __syncthreads();
  if (tid < K) off[tid * nblkE + blk] = lh[tid];
}

// partition pass: write (src, dst&255) into per-(chunk,bucket) runs
__global__ void part_kernel(const int* __restrict__ ei, int E, int nblkE, int K,
                            const int* __restrict__ off, int* __restrict__ psrc,
                            unsigned short* __restrict__ pld) {
  __shared__ int lcur[256];
  int tid = threadIdx.x, blk = blockIdx.x;
  if (tid < K) lcur[tid] = off[tid * nblkE + blk];
  __syncthreads();
  int e0 = blk * 8192;
  for (int i = tid; i < 8192; i += 256) {
    int e = e0 + i;
    if (e < E) {
      int s = ei[e], d = ei[E + e];
      int pos = atomicAdd(&lcur[d >> 8], 1);
      psrc[pos] = s;
      pld[pos] = (unsigned short)(d & 255);
    }
  }
}

// final CSR: one block per bucket; cursor from rowptr; bucket-local writes
__global__ void csr_kernel(const int* __restrict__ off, int nblkE, int K,
                           const int* __restrict__ rowptr, const int* __restrict__ psrc,
                           const unsigned short* __restrict__ pld,
                           int* __restrict__ esrc, int N, int E) {
  __shared__ int lcur[256];
  int tid = threadIdx.x, b = blockIdx.x;
  int node = (b << 8) + tid;
  lcur[tid] = (node < N) ? rowptr[node] : 0;
  __syncthreads();
  int be0 = off[b * nblkE];
  int be1 = (b + 1 < K) ? off[(b + 1) * nblkE] : E;
  for (int i = be0 + tid; i < be1; i += 256) {
    int s = psrc[i];
    int ld = pld[i];
    int pos = atomicAdd(&lcur[ld], 1);
    esrc[pos] = s;
  }
}

// ---- layer 1 fused: wave per node; gather xs; h1p = dis*relu(aggr@W1+b1) --
__global__ void l1_kernel(const int* __restrict__ rowptr, const int* __restrict__ cnt,
                          const int* __restrict__ esrc, const float* __restrict__ xs,
                          const float* __restrict__ x, const float* __restrict__ dis,
                          const float* __restrict__ W1, const float* __restrict__ b1,
                          float* __restrict__ h1p, int N) {
  int tid = threadIdx.x;
  int lane = tid & 63, wid = tid >> 6;
  int d = __builtin_amdgcn_readfirstlane(blockIdx.x * 4 + wid);
  if (d >= N) return;
  float di = dis[d];
  int p = __builtin_amdgcn_readfirstlane(rowptr[d]);
  int n = __builtin_amdgcn_readfirstlane(cnt[d]);
  float a0 = 0.f, a1 = 0.f, a2 = 0.f, a3 = 0.f;
  for (int k = lane; k < n; k += 64) {
    int e = esrc[p + k];
    float4 v = ((const float4*)xs)[e];
    a0 += v.x; a1 += v.y; a2 += v.z; a3 += v.w;
  }
  if (lane == 0) {  // self loop: + di*x[d]
    float4 xv = ((const float4*)x)[d];
    a0 = fmaf(di, xv.x, a0); a1 = fmaf(di, xv.y, a1);
    a2 = fmaf(di, xv.z, a2); a3 = fmaf(di, xv.w, a3);
  }
#pragma unroll
  for (int off = 1; off < 64; off <<= 1) {
    a0 += __shfl_xor(a0, off, 64);
    a1 += __shfl_xor(a1, off, 64);
    a2 += __shfl_xor(a2, off, 64);
    a3 += __shfl_xor(a3, off, 64);
  }
  a0 *= di; a1 *= di; a2 *= di; a3 *= di;
  float o = b1[lane] + a0 * W1[lane] + a1 * W1[64 + lane] + a2 * W1[128 + lane] + a3 * W1[192 + lane];
  h1p[(long)d * 64 + lane] = di * fmaxf(o, 0.0f);
}

// ---- layer 2: weightless gather (unroll-8) + matmul + relu + pooled -----
__global__ void __launch_bounds__(512)
l2_kernel(const int* __restrict__ rowptr, const int* __restrict__ cnt,
          const int* __restrict__ esrc, const float* __restrict__ h1p,
          const float* __restrict__ dis, const float* __restrict__ W2,
          const float* __restrict__ b2, const int* __restrict__ batch,
          float* __restrict__ gsum, int N) {
  __shared__ float vbuf[8][64];
  __shared__ float obuf[8][64];
  __shared__ int gbuf[8];
  int tid = threadIdx.x;
  int lane = tid & 63, wid = tid >> 6;
  int d0 = blockIdx.x * 8 + wid;
  bool valid = d0 < N;
  int d = __builtin_amdgcn_readfirstlane(valid ? d0 : N - 1);
  float di = dis[d];
  float acc0 = h1p[(long)d * 64 + lane];  // self loop (h1p already has dis factor)
  float acc1 = 0.f, acc2 = 0.f, acc3 = 0.f;
  float acc4 = 0.f, acc5 = 0.f, acc6 = 0.f, acc7 = 0.f;
  int p = __builtin_amdgcn_readfirstlane(rowptr[d]);
  int n = __builtin_amdgcn_readfirstlane(cnt[d]);
  int k = 0;
  for (; k + 8 <= n; k += 8) {
    int e0 = esrc[p + k + 0], e1 = esrc[p + k + 1];
    int e2 = esrc[p + k + 2], e3 = esrc[p + k + 3];
    int e4 = esrc[p + k + 4], e5 = esrc[p + k + 5];
    int e6 = esrc[p + k + 6], e7 = esrc[p + k + 7];
    acc0 += h1p[(long)e0 * 64 + lane];
    acc1 += h1p[(long)e1 * 64 + lane];
    acc2 += h1p[(long)e2 * 64 + lane];
    acc3 += h1p[(long)e3 * 64 + lane];
    acc4 += h1p[(long)e4 * 64 + lane];
    acc5 += h1p[(long)e5 * 64 + lane];
    acc6 += h1p[(long)e6 * 64 + lane];
    acc7 += h1p[(long)e7 * 64 + lane];
  }
  if (k < n) {
#pragma unroll
    for (int i = 0; i < 7; ++i) {
      int idx = k + i;
      int safe = (idx < n) ? idx : (n - 1);
      float m = (idx < n) ? 1.0f : 0.0f;
      int e = esrc[p + safe];
      float v = h1p[(long)e * 64 + lane];
      switch (i & 3) {
        case 0: acc1 = fmaf(m, v, acc1); break;
        case 1: acc2 = fmaf(m, v, acc2); break;
        case 2: acc3 = fmaf(m, v, acc3); break;
        case 3: acc4 = fmaf(m, v, acc4); break;
      }
    }
  }
  float v = di * (((acc0 + acc1) + (acc2 + acc3)) + ((acc4 + acc5) + (acc6 + acc7)));
  vbuf[wid][lane] = v;  // intra-wave, in-order
  float o = b2[lane];
  const float4* vb4 = (const float4*)vbuf[wid];
#pragma unroll
  for (int kk = 0; kk < 16; ++kk) {
    float4 vv = vb4[kk];  // uniform address -> broadcast read
    o = fmaf(vv.x, W2[(kk * 4 + 0) * 64 + lane], o);
    o = fmaf(vv.y, W2[(kk * 4 + 1) * 64 + lane], o);
    o = fmaf(vv.z, W2[(kk * 4 + 2) * 64 + lane], o);
    o = fmaf(vv.w, W2[(kk * 4 + 3) * 64 + lane], o);
  }
  obuf[wid][lane] = fmaxf(o, 0.0f);
  if (lane == 0) gbuf[wid] = valid ? batch[d] : -1;
  __syncthreads();
  if (wid == 0) {
    float s = 0.0f;
    int cur = gbuf[0];
#pragma unroll
    for (int r = 0; r < 8; ++r) {
      int g = gbuf[r];
      if (g != cur) {
        if (cur >= 0) atomicAdd(&gsum[cur * 64 + lane], s);
        s = 0.0f;
        cur = g;
      }
      if (g >= 0) s += obuf[r][lane];
    }
    if (cur >= 0) atomicAdd(&gsum[cur * 64 + lane], s);
  }
}

// ---- output: mean via binary search on sorted batch ---------------------

__device__ __forceinline__ int lbound(const int* __restrict__ a, int n, int v) {
  int lo = 0, hi = n;
  while (lo < hi) {
    int mid = (lo + hi) >> 1;
    if (a[mid] < v) lo = mid + 1; else hi = mid;
  }
  return lo;
}

__global__ void out_kernel(const float* __restrict__ gsum, const int* __restrict__ batch,
                           int N, float* __restrict__ out) {
  int t = blockIdx.x * blockDim.x + threadIdx.x;
  if (t >= NG * 64) return;
  int g = t >> 6;
  int cnt = lbound(batch, N, g + 1) - lbound(batch, N, g);
  out[t] = gsum[t] / fmaxf((float)cnt, 1.0f);
}

// ---- launch --------------------------------------------------------------

extern "C" void kernel_launch(void* const* d_in, const int* in_sizes, int n_in,
                              void* d_out, int out_size, void* d_ws, size_t ws_size,
                              hipStream_t stream) {
  const float* x = (const float*)d_in[0];
  const int* ei = (const int*)d_in[1];     // [2,E]: src row then dst row
  const int* batch = (const int*)d_in[2];  // sorted graph ids
  const float* W1 = (const float*)d_in[4];
  const float* b1 = (const float*)d_in[5];
  const float* W2 = (const float*)d_in[6];
  const float* b2 = (const float*)d_in[7];

  const int N = in_sizes[0] / 4;
  const int E = in_sizes[1] / 2;
  const int NB1 = (N + 255) / 256;          // node-scan blocks
  const int K = (N + 255) >> 8;             // buckets (dst>>8)
  const int nblkE = (E + 8191) / 8192;      // edge chunks
  const int M2 = K * nblkE;                 // off array size
  const int NB2 = (M2 + 255) / 256;

  // ws layout (4B units):
  // [cnt N][gsum 64*NG] <- zeroed each call
  // [xs 4N][rowptr N][esrc E][dis N][h1p 64N][bsum1 NB1][off M2][bsum2 NB2]
  // [psrc E][pld E/2 (ushorts)]
  int* cnt = (int*)d_ws;
  float* gsum = (float*)(cnt + N);
  float* xs = gsum + 64 * NG;
  int* rowptr = (int*)(xs + (long)4 * N);
  int* esrc = rowptr + N;
  float* dis = (float*)(esrc + E);
  float* h1p = dis + N;
  int* bsum1 = (int*)(h1p + (long)64 * N);
  int* off = bsum1 + 1024;
  int* bsum2 = off + M2;
  int* psrc = bsum2 + 1024;
  unsigned short* pld = (unsigned short*)(psrc + E);

  size_t zero_bytes = ((size_t)N + 64 * NG) * 4;
  hipMemsetAsync(d_ws, 0, zero_bytes, stream);

  const int B = 256;
  cnt_kernel<<<(E + B - 1) / B, B, 0, stream>>>(ei, E, cnt);
  bsum_kernel<<<NB1, 256, 0, stream>>>(cnt, bsum1, N);
  bscan_kernel<<<1, 1024, 0, stream>>>(bsum1, NB1);
  rowptr_kernel<<<NB1, 256, 0, stream>>>(cnt, bsum1, rowptr, dis, x, xs, N);
  hist_kernel<<<nblkE, 256, 0, stream>>>(ei, E, nblkE, K, off);
  bsum_kernel<<<NB2, 256, 0, stream>>>(off, bsum2, M2);
  bscan_kernel<<<1, 1024, 0, stream>>>(bsum2, NB2);
  offadd_kernel<<<NB2, 256, 0, stream>>>(off, bsum2, M2);
  part_kernel<<<nblkE, 256, 0, stream>>>(ei, E, nblkE, K, off, psrc, pld);
  csr_kernel<<<K, 256, 0, stream>>>(off, nblkE, K, rowptr, psrc, pld, esrc, N, E);
  l1_kernel<<<(N + 3) / 4, 256, 0, stream>>>(rowptr, cnt, esrc, xs, x, dis, W1, b1, h1p, N);
  l2_kernel<<<(N + 7) / 8, 512, 0, stream>>>(rowptr, cnt, esrc, h1p, dis, W2, b2, batch, gsum, N);
  out_kernel<<<(NG * 64 + B - 1) / B, B, 0, stream>>>(gsum, batch, N, (float*)d_out);
}

// Round 10
// 131.604 us; speedup vs baseline: 1.4693x; 1.2956x over previous
//
#include <hip/hip_runtime.h>
#include <hip/hip_fp16.h>

#define NG 128

__device__ __forceinline__ int wave_iscan(int v, int lane) {
#pragma unroll
  for (int off = 1; off < 64; off <<= 1) {
    int u = __shfl_up(v, off, 64);
    if (lane >= off) v += u;
  }
  return v;
}

// ---- generic scan helpers (for the off array) ---------------------------

__global__ void bsum_kernel(const int* __restrict__ src, int* __restrict__ bsum, int M) {
  __shared__ int wsum[4];
  int tid = threadIdx.x, lane = tid & 63, wid = tid >> 6;
  int i = blockIdx.x * 256 + tid;
  int v = (i < M) ? src[i] : 0;
  int inc = wave_iscan(v, lane);
  if (lane == 63) wsum[wid] = inc;
  __syncthreads();
  if (tid == 0) bsum[blockIdx.x] = wsum[0] + wsum[1] + wsum[2] + wsum[3];
}

__global__ void bscan_kernel(int* __restrict__ bsum, int nb) {
  __shared__ int wsum[16];
  int tid = threadIdx.x, lane = tid & 63, wid = tid >> 6;
  int v = (tid < nb) ? bsum[tid] : 0;
  int inc = wave_iscan(v, lane);
  if (lane == 63) wsum[wid] = inc;
  __syncthreads();
  if (tid == 0) {
    int a = 0;
#pragma unroll
    for (int w = 0; w < 16; ++w) { int t = wsum[w]; wsum[w] = a; a += t; }
  }
  __syncthreads();
  if (tid < nb) bsum[tid] = inc - v + wsum[wid];
}

__global__ void offadd_kernel(int* __restrict__ off, const int* __restrict__ bsum, int M) {
  __shared__ int wsum[4];
  int tid = threadIdx.x, lane = tid & 63, wid = tid >> 6;
  int i = blockIdx.x * 256 + tid;
  int v = (i < M) ? off[i] : 0;
  int inc = wave_iscan(v, lane);
  if (lane == 63) wsum[wid] = inc;
  __syncthreads();
  if (tid == 0) {
    int a = bsum[blockIdx.x];
#pragma unroll
    for (int w = 0; w < 4; ++w) { int t = wsum[w]; wsum[w] = a; a += t; }
  }
  __syncthreads();
  if (i < M) off[i] = inc - v + wsum[wid];
}

// ---- bucketed edge reorder (bucket = dst >> 8) --------------------------

__global__ void hist_kernel(const int* __restrict__ ei, int E, int nblkE, int K,
                            int* __restrict__ off) {
  __shared__ int lh[256];
  int tid = threadIdx.x, blk = blockIdx.x;
  lh[tid] = 0;
  __syncthreads();
  int e0 = blk * 8192;
  for (int i = tid; i < 8192; i += 256) {
    int e = e0 + i;
    if (e < E) atomicAdd(&lh[ei[E + e] >> 8], 1);
  }
  __syncthreads();
  if (tid < K) off[tid * nblkE + blk] = lh[tid];
}

__global__ void part_kernel(const int* __restrict__ ei, int E, int nblkE, int K,
                            const int* __restrict__ off, int* __restrict__ psrc,
                            unsigned short* __restrict__ pld) {
  __shared__ int lcur[256];
  int tid = threadIdx.x, blk = blockIdx.x;
  if (tid < K) lcur[tid] = off[tid * nblkE + blk];
  __syncthreads();
  int e0 = blk * 8192;
  for (int i = tid; i < 8192; i += 256) {
    int e = e0 + i;
    if (e < E) {
      int s = ei[e], d = ei[E + e];
      int pos = atomicAdd(&lcur[d >> 8], 1);
      psrc[pos] = s;
      pld[pos] = (unsigned short)(d & 255);
    }
  }
}

// one block per bucket: local degree count + scan -> rowptr/deg/dis/xs,
// then cursor fill of esrc. Replaces cnt_kernel + node scans entirely.
__global__ void csr2_kernel(const int* __restrict__ off, int nblkE, int K,
                            const int* __restrict__ psrc,
                            const unsigned short* __restrict__ pld,
                            const float* __restrict__ x, int* __restrict__ deg,
                            int* __restrict__ rowptr, float* __restrict__ dis,
                            float* __restrict__ xs, int* __restrict__ esrc,
                            int N, int E) {
  __shared__ int lcnt[256];
  __shared__ int lcur[256];
  __shared__ int wsum[4];
  int tid = threadIdx.x, b = blockIdx.x;
  int lane = tid & 63, wid = tid >> 6;
  lcnt[tid] = 0;
  __syncthreads();
  int be0 = off[b * nblkE];
  int be1 = (b + 1 < K) ? off[(b + 1) * nblkE] : E;
  for (int i = be0 + tid; i < be1; i += 256) atomicAdd(&lcnt[pld[i]], 1);
  __syncthreads();
  int v = lcnt[tid];
  int inc = wave_iscan(v, lane);
  if (lane == 63) wsum[wid] = inc;
  __syncthreads();
  if (tid == 0) {
    int a = be0;
#pragma unroll
    for (int w = 0; w < 4; ++w) { int t = wsum[w]; wsum[w] = a; a += t; }
  }
  __syncthreads();
  int exc = inc - v + wsum[wid];
  lcur[tid] = exc;
  int node = (b << 8) + tid;
  if (node < N) {
    rowptr[node] = exc;
    deg[node] = v;
    float di = rsqrtf((float)v + 1.0f);  // +1 self loop
    dis[node] = di;
    float4 xv = ((const float4*)x)[node];
    ((float4*)xs)[node] = make_float4(di * xv.x, di * xv.y, di * xv.z, di * xv.w);
  }
  __syncthreads();
  for (int i = be0 + tid; i < be1; i += 256) {
    int pos = atomicAdd(&lcur[pld[i]], 1);
    esrc[pos] = psrc[i];
  }
}

// ---- layer 1 fused: wave per node; gather xs; h1p = fp16(dis*relu(a@W1+b1))
__global__ void l1_kernel(const int* __restrict__ rowptr, const int* __restrict__ deg,
                          const int* __restrict__ esrc, const float* __restrict__ xs,
                          const float* __restrict__ x, const float* __restrict__ dis,
                          const float* __restrict__ W1, const float* __restrict__ b1,
                          __half* __restrict__ h1p, int N) {
  int tid = threadIdx.x;
  int lane = tid & 63, wid = tid >> 6;
  int d = __builtin_amdgcn_readfirstlane(blockIdx.x * 4 + wid);
  if (d >= N) return;
  float di = dis[d];
  int p = __builtin_amdgcn_readfirstlane(rowptr[d]);
  int n = __builtin_amdgcn_readfirstlane(deg[d]);
  float a0 = 0.f, a1 = 0.f, a2 = 0.f, a3 = 0.f;
  for (int k = lane; k < n; k += 64) {
    int e = esrc[p + k];
    float4 v = ((const float4*)xs)[e];
    a0 += v.x; a1 += v.y; a2 += v.z; a3 += v.w;
  }
  if (lane == 0) {  // self loop: + di*x[d]
    float4 xv = ((const float4*)x)[d];
    a0 = fmaf(di, xv.x, a0); a1 = fmaf(di, xv.y, a1);
    a2 = fmaf(di, xv.z, a2); a3 = fmaf(di, xv.w, a3);
  }
#pragma unroll
  for (int off = 1; off < 64; off <<= 1) {
    a0 += __shfl_xor(a0, off, 64);
    a1 += __shfl_xor(a1, off, 64);
    a2 += __shfl_xor(a2, off, 64);
    a3 += __shfl_xor(a3, off, 64);
  }
  a0 *= di; a1 *= di; a2 *= di; a3 *= di;
  float o = b1[lane] + a0 * W1[lane] + a1 * W1[64 + lane] + a2 * W1[128 + lane] + a3 * W1[192 + lane];
  h1p[(long)d * 64 + lane] = __float2half(di * fmaxf(o, 0.0f));
}

// ---- layer 2: fp16 weightless gather (unroll-8) + matmul + pooled -------
__global__ void __launch_bounds__(512)
l2_kernel(const int* __restrict__ rowptr, const int* __restrict__ deg,
          const int* __restrict__ esrc, const __half* __restrict__ h1p,
          const float* __restrict__ dis, const float* __restrict__ W2,
          const float* __restrict__ b2, const int* __restrict__ batch,
          float* __restrict__ gsum, int N) {
  __shared__ float vbuf[8][64];
  __shared__ float obuf[8][64];
  __shared__ int gbuf[8];
  int tid = threadIdx.x;
  int lane = tid & 63, wid = tid >> 6;
  int d0 = blockIdx.x * 8 + wid;
  bool valid = d0 < N;
  int d = __builtin_amdgcn_readfirstlane(valid ? d0 : N - 1);
  float di = dis[d];
  float acc0 = __half2float(h1p[(long)d * 64 + lane]);  // self loop
  float acc1 = 0.f, acc2 = 0.f, acc3 = 0.f;
  float acc4 = 0.f, acc5 = 0.f, acc6 = 0.f, acc7 = 0.f;
  int p = __builtin_amdgcn_readfirstlane(rowptr[d]);
  int n = __builtin_amdgcn_readfirstlane(deg[d]);
  int k = 0;
  for (; k + 8 <= n; k += 8) {
    int e0 = esrc[p + k + 0], e1 = esrc[p + k + 1];
    int e2 = esrc[p + k + 2], e3 = esrc[p + k + 3];
    int e4 = esrc[p + k + 4], e5 = esrc[p + k + 5];
    int e6 = esrc[p + k + 6], e7 = esrc[p + k + 7];
    acc0 += __half2float(h1p[(long)e0 * 64 + lane]);
    acc1 += __half2float(h1p[(long)e1 * 64 + lane]);
    acc2 += __half2float(h1p[(long)e2 * 64 + lane]);
    acc3 += __half2float(h1p[(long)e3 * 64 + lane]);
    acc4 += __half2float(h1p[(long)e4 * 64 + lane]);
    acc5 += __half2float(h1p[(long)e5 * 64 + lane]);
    acc6 += __half2float(h1p[(long)e6 * 64 + lane]);
    acc7 += __half2float(h1p[(long)e7 * 64 + lane]);
  }
  if (k < n) {
#pragma unroll
    for (int i = 0; i < 7; ++i) {
      int idx = k + i;
      int safe = (idx < n) ? idx : (n - 1);
      float m = (idx < n) ? 1.0f : 0.0f;
      int e = esrc[p + safe];
      float v = __half2float(h1p[(long)e * 64 + lane]);
      switch (i & 3) {
        case 0: acc1 = fmaf(m, v, acc1); break;
        case 1: acc2 = fmaf(m, v, acc2); break;
        case 2: acc3 = fmaf(m, v, acc3); break;
        case 3: acc4 = fmaf(m, v, acc4); break;
      }
    }
  }
  float v = di * (((acc0 + acc1) + (acc2 + acc3)) + ((acc4 + acc5) + (acc6 + acc7)));
  vbuf[wid][lane] = v;  // intra-wave, in-order
  float o = b2[lane];
  const float4* vb4 = (const float4*)vbuf[wid];
#pragma unroll
  for (int kk = 0; kk < 16; ++kk) {
    float4 vv = vb4[kk];  // uniform address -> broadcast read
    o = fmaf(vv.x, W2[(kk * 4 + 0) * 64 + lane], o);
    o = fmaf(vv.y, W2[(kk * 4 + 1) * 64 + lane], o);
    o = fmaf(vv.z, W2[(kk * 4 + 2) * 64 + lane], o);
    o = fmaf(vv.w, W2[(kk * 4 + 3) * 64 + lane], o);
  }
  obuf[wid][lane] = fmaxf(o, 0.0f);
  if (lane == 0) gbuf[wid] = valid ? batch[d] : -1;
  __syncthreads();
  if (wid == 0) {
    float s = 0.0f;
    int cur = gbuf[0];
#pragma unroll
    for (int r = 0; r < 8; ++r) {
      int g = gbuf[r];
      if (g != cur) {
        if (cur >= 0) atomicAdd(&gsum[cur * 64 + lane], s);
        s = 0.0f;
        cur = g;
      }
      if (g >= 0) s += obuf[r][lane];
    }
    if (cur >= 0) atomicAdd(&gsum[cur * 64 + lane], s);
  }
}

// ---- output: mean via binary search on sorted batch ---------------------

__device__ __forceinline__ int lbound(const int* __restrict__ a, int n, int v) {
  int lo = 0, hi = n;
  while (lo < hi) {
    int mid = (lo + hi) >> 1;
    if (a[mid] < v) lo = mid + 1; else hi = mid;
  }
  return lo;
}

__global__ void out_kernel(const float* __restrict__ gsum, const int* __restrict__ batch,
                           int N, float* __restrict__ out) {
  int t = blockIdx.x * blockDim.x + threadIdx.x;
  if (t >= NG * 64) return;
  int g = t >> 6;
  int cnt = lbound(batch, N, g + 1) - lbound(batch, N, g);
  out[t] = gsum[t] / fmaxf((float)cnt, 1.0f);
}

// ---- launch --------------------------------------------------------------

extern "C" void kernel_launch(void* const* d_in, const int* in_sizes, int n_in,
                              void* d_out, int out_size, void* d_ws, size_t ws_size,
                              hipStream_t stream) {
  const float* x = (const float*)d_in[0];
  const int* ei = (const int*)d_in[1];     // [2,E]: src row then dst row
  const int* batch = (const int*)d_in[2];  // sorted graph ids
  const float* W1 = (const float*)d_in[4];
  const float* b1 = (const float*)d_in[5];
  const float* W2 = (const float*)d_in[6];
  const float* b2 = (const float*)d_in[7];

  const int N = in_sizes[0] / 4;
  const int E = in_sizes[1] / 2;
  const int K = (N + 255) >> 8;             // buckets (dst>>8)
  const int nblkE = (E + 8191) / 8192;      // edge chunks
  const int M2 = K * nblkE;
  const int NB2 = (M2 + 255) / 256;         // <= 1024

  // ws layout (4B units unless noted):
  // [gsum 64*NG] <- zeroed each call
  // [deg N][rowptr N][xs 4N][dis N][h1p 64N halves][off M2][bsum2 1024]
  // [psrc E][pld E ushorts][esrc E]
  float* gsum = (float*)d_ws;
  int* deg = (int*)(gsum + 64 * NG);
  int* rowptr = deg + N;
  float* xs = (float*)(rowptr + N);         // offset 8192+2N floats, %4==0 -> 16B aligned
  float* dis = xs + (long)4 * N;
  __half* h1p = (__half*)(dis + N);
  int* off = (int*)(dis + N + (long)32 * N);
  int* bsum2 = off + M2;
  int* psrc = bsum2 + 1024;
  unsigned short* pld = (unsigned short*)(psrc + E);
  int* esrc = (int*)(pld + E);              // E even -> 4B aligned

  hipMemsetAsync(d_ws, 0, (size_t)64 * NG * 4, stream);

  const int B = 256;
  hist_kernel<<<nblkE, 256, 0, stream>>>(ei, E, nblkE, K, off);
  bsum_kernel<<<NB2, 256, 0, stream>>>(off, bsum2, M2);
  bscan_kernel<<<1, 1024, 0, stream>>>(bsum2, NB2);
  offadd_kernel<<<NB2, 256, 0, stream>>>(off, bsum2, M2);
  part_kernel<<<nblkE, 256, 0, stream>>>(ei, E, nblkE, K, off, psrc, pld);
  csr2_kernel<<<K, 256, 0, stream>>>(off, nblkE, K, psrc, pld, x, deg, rowptr, dis, xs, esrc, N, E);
  l1_kernel<<<(N + 3) / 4, 256, 0, stream>>>(rowptr, deg, esrc, xs, x, dis, W1, b1, h1p, N);
  l2_kernel<<<(N + 7) / 8, 512, 0, stream>>>(rowptr, deg, esrc, h1p, dis, W2, b2, batch, gsum, N);
  out_kernel<<<(NG * 64 + B - 1) / B, B, 0, stream>>>(gsum, batch, N, (float*)d_out);
}

// Round 11
// 120.083 us; speedup vs baseline: 1.6103x; 1.0959x over previous
//
#include <hip/hip_runtime.h>
#include <hip/hip_fp16.h>

#define NG 128
#define CHUNK 4096

__device__ __forceinline__ int wave_iscan(int v, int lane) {
#pragma unroll
  for (int off = 1; off < 64; off <<= 1) {
    int u = __shfl_up(v, off, 64);
    if (lane >= off) v += u;
  }
  return v;
}

// ---- generic scan helpers (for the off array) ---------------------------

__global__ void bsum_kernel(const int* __restrict__ src, int* __restrict__ bsum, int M) {
  __shared__ int wsum[4];
  int tid = threadIdx.x, lane = tid & 63, wid = tid >> 6;
  int i = blockIdx.x * 256 + tid;
  int v = (i < M) ? src[i] : 0;
  int inc = wave_iscan(v, lane);
  if (lane == 63) wsum[wid] = inc;
  __syncthreads();
  if (tid == 0) bsum[blockIdx.x] = wsum[0] + wsum[1] + wsum[2] + wsum[3];
}

__global__ void bscan_kernel(int* __restrict__ bsum, int nb) {
  __shared__ int wsum[16];
  int tid = threadIdx.x, lane = tid & 63, wid = tid >> 6;
  int v = (tid < nb) ? bsum[tid] : 0;
  int inc = wave_iscan(v, lane);
  if (lane == 63) wsum[wid] = inc;
  __syncthreads();
  if (tid == 0) {
    int a = 0;
#pragma unroll
    for (int w = 0; w < 16; ++w) { int t = wsum[w]; wsum[w] = a; a += t; }
  }
  __syncthreads();
  if (tid < nb) bsum[tid] = inc - v + wsum[wid];
}

__global__ void offadd_kernel(int* __restrict__ off, const int* __restrict__ bsum, int M) {
  __shared__ int wsum[4];
  int tid = threadIdx.x, lane = tid & 63, wid = tid >> 6;
  int i = blockIdx.x * 256 + tid;
  int v = (i < M) ? off[i] : 0;
  int inc = wave_iscan(v, lane);
  if (lane == 63) wsum[wid] = inc;
  __syncthreads();
  if (tid == 0) {
    int a = bsum[blockIdx.x];
#pragma unroll
    for (int w = 0; w < 4; ++w) { int t = wsum[w]; wsum[w] = a; a += t; }
  }
  __syncthreads();
  if (i < M) off[i] = inc - v + wsum[wid];
}

// ---- bucketed edge reorder (bucket = dst >> 8) --------------------------

__global__ void hist_kernel(const int* __restrict__ ei, int E, int nblkE, int K,
                            int* __restrict__ off) {
  __shared__ int lh[256];
  int tid = threadIdx.x, blk = blockIdx.x;
  lh[tid] = 0;
  __syncthreads();
  int e0 = blk * CHUNK;
  for (int i = tid; i < CHUNK; i += 256) {
    int e = e0 + i;
    if (e < E) atomicAdd(&lh[ei[E + e] >> 8], 1);
  }
  __syncthreads();
  if (tid < K) off[tid * nblkE + blk] = lh[tid];
}

__global__ void part_kernel(const int* __restrict__ ei, int E, int nblkE, int K,
                            const int* __restrict__ off, int* __restrict__ psrc,
                            unsigned short* __restrict__ pld) {
  __shared__ int lcur[256];
  int tid = threadIdx.x, blk = blockIdx.x;
  if (tid < K) lcur[tid] = off[tid * nblkE + blk];
  __syncthreads();
  int e0 = blk * CHUNK;
  for (int i = tid; i < CHUNK; i += 256) {
    int e = e0 + i;
    if (e < E) {
      int s = ei[e], d = ei[E + e];
      int pos = atomicAdd(&lcur[d >> 8], 1);
      psrc[pos] = s;
      pld[pos] = (unsigned short)(d & 255);
    }
  }
}

// one block per bucket: local degree count + scan -> rowptr/deg/dis/xs,
// then cursor fill of esrc. Replaces cnt_kernel + node scans entirely.
__global__ void csr2_kernel(const int* __restrict__ off, int nblkE, int K,
                            const int* __restrict__ psrc,
                            const unsigned short* __restrict__ pld,
                            const float* __restrict__ x, int* __restrict__ deg,
                            int* __restrict__ rowptr, float* __restrict__ dis,
                            float* __restrict__ xs, int* __restrict__ esrc,
                            int N, int E) {
  __shared__ int lcnt[256];
  __shared__ int lcur[256];
  __shared__ int wsum[4];
  int tid = threadIdx.x, b = blockIdx.x;
  int lane = tid & 63, wid = tid >> 6;
  lcnt[tid] = 0;
  __syncthreads();
  int be0 = off[b * nblkE];
  int be1 = (b + 1 < K) ? off[(b + 1) * nblkE] : E;
  for (int i = be0 + tid; i < be1; i += 256) atomicAdd(&lcnt[pld[i]], 1);
  __syncthreads();
  int v = lcnt[tid];
  int inc = wave_iscan(v, lane);
  if (lane == 63) wsum[wid] = inc;
  __syncthreads();
  if (tid == 0) {
    int a = be0;
#pragma unroll
    for (int w = 0; w < 4; ++w) { int t = wsum[w]; wsum[w] = a; a += t; }
  }
  __syncthreads();
  int exc = inc - v + wsum[wid];
  lcur[tid] = exc;
  int node = (b << 8) + tid;
  if (node < N) {
    rowptr[node] = exc;
    deg[node] = v;
    float di = rsqrtf((float)v + 1.0f);  // +1 self loop
    dis[node] = di;
    float4 xv = ((const float4*)x)[node];
    ((float4*)xs)[node] = make_float4(di * xv.x, di * xv.y, di * xv.z, di * xv.w);
  }
  __syncthreads();
  for (int i = be0 + tid; i < be1; i += 256) {
    int pos = atomicAdd(&lcur[pld[i]], 1);
    esrc[pos] = psrc[i];
  }
}

// ---- layer 1 fused: wave per node; gather xs; h1p = fp16(dis*relu(a@W1+b1))
__global__ void l1_kernel(const int* __restrict__ rowptr, const int* __restrict__ deg,
                          const int* __restrict__ esrc, const float* __restrict__ xs,
                          const float* __restrict__ x, const float* __restrict__ dis,
                          const float* __restrict__ W1, const float* __restrict__ b1,
                          __half* __restrict__ h1p, int N) {
  int tid = threadIdx.x;
  int lane = tid & 63, wid = tid >> 6;
  int d = __builtin_amdgcn_readfirstlane(blockIdx.x * 4 + wid);
  if (d >= N) return;
  float di = dis[d];
  int p = __builtin_amdgcn_readfirstlane(rowptr[d]);
  int n = __builtin_amdgcn_readfirstlane(deg[d]);
  float a0 = 0.f, a1 = 0.f, a2 = 0.f, a3 = 0.f;
  for (int k = lane; k < n; k += 64) {
    int e = esrc[p + k];
    float4 v = ((const float4*)xs)[e];
    a0 += v.x; a1 += v.y; a2 += v.z; a3 += v.w;
  }
  if (lane == 0) {  // self loop: + di*x[d]
    float4 xv = ((const float4*)x)[d];
    a0 = fmaf(di, xv.x, a0); a1 = fmaf(di, xv.y, a1);
    a2 = fmaf(di, xv.z, a2); a3 = fmaf(di, xv.w, a3);
  }
#pragma unroll
  for (int off = 1; off < 64; off <<= 1) {
    a0 += __shfl_xor(a0, off, 64);
    a1 += __shfl_xor(a1, off, 64);
    a2 += __shfl_xor(a2, off, 64);
    a3 += __shfl_xor(a3, off, 64);
  }
  a0 *= di; a1 *= di; a2 *= di; a3 *= di;
  float o = b1[lane] + a0 * W1[lane] + a1 * W1[64 + lane] + a2 * W1[128 + lane] + a3 * W1[192 + lane];
  h1p[(long)d * 64 + lane] = __float2half(di * fmaxf(o, 0.0f));
}

// ---- layer 2: fp16 gather, masked unroll-16, matmul + pooled ------------
__global__ void __launch_bounds__(256)
l2_kernel(const int* __restrict__ rowptr, const int* __restrict__ deg,
          const int* __restrict__ esrc, const __half* __restrict__ h1p,
          const float* __restrict__ dis, const float* __restrict__ W2,
          const float* __restrict__ b2, const int* __restrict__ batch,
          float* __restrict__ gsum, int N) {
  __shared__ float vbuf[4][64];
  __shared__ float obuf[4][64];
  __shared__ int gbuf[4];
  int tid = threadIdx.x;
  int lane = tid & 63, wid = tid >> 6;
  int d0 = blockIdx.x * 4 + wid;
  bool valid = d0 < N;
  int d = __builtin_amdgcn_readfirstlane(valid ? d0 : N - 1);
  float di = dis[d];
  float acc0 = __half2float(h1p[(long)d * 64 + lane]);  // self loop
  float acc1 = 0.f, acc2 = 0.f, acc3 = 0.f;
  float acc4 = 0.f, acc5 = 0.f, acc6 = 0.f, acc7 = 0.f;
  int p = __builtin_amdgcn_readfirstlane(rowptr[d]);
  int n = __builtin_amdgcn_readfirstlane(deg[d]);
  for (int k = 0; k < n; k += 16) {
    int es[16];
#pragma unroll
    for (int i = 0; i < 16; ++i) {
      int idx = k + i;
      es[i] = esrc[p + ((idx < n) ? idx : (n - 1))];  // uniform scalar loads
    }
#pragma unroll
    for (int i = 0; i < 16; ++i) {
      float m = (k + i < n) ? 1.0f : 0.0f;
      float v = __half2float(h1p[(long)es[i] * 64 + lane]);
      switch (i & 7) {
        case 0: acc0 = fmaf(m, v, acc0); break;
        case 1: acc1 = fmaf(m, v, acc1); break;
        case 2: acc2 = fmaf(m, v, acc2); break;
        case 3: acc3 = fmaf(m, v, acc3); break;
        case 4: acc4 = fmaf(m, v, acc4); break;
        case 5: acc5 = fmaf(m, v, acc5); break;
        case 6: acc6 = fmaf(m, v, acc6); break;
        case 7: acc7 = fmaf(m, v, acc7); break;
      }
    }
  }
  float v = di * (((acc0 + acc1) + (acc2 + acc3)) + ((acc4 + acc5) + (acc6 + acc7)));
  vbuf[wid][lane] = v;  // intra-wave, in-order
  float o = b2[lane];
  const float4* vb4 = (const float4*)vbuf[wid];
#pragma unroll
  for (int kk = 0; kk < 16; ++kk) {
    float4 vv = vb4[kk];  // uniform address -> broadcast read
    o = fmaf(vv.x, W2[(kk * 4 + 0) * 64 + lane], o);
    o = fmaf(vv.y, W2[(kk * 4 + 1) * 64 + lane], o);
    o = fmaf(vv.z, W2[(kk * 4 + 2) * 64 + lane], o);
    o = fmaf(vv.w, W2[(kk * 4 + 3) * 64 + lane], o);
  }
  obuf[wid][lane] = fmaxf(o, 0.0f);
  if (lane == 0) gbuf[wid] = valid ? batch[d] : -1;
  __syncthreads();
  if (wid == 0) {
    float s = 0.0f;
    int cur = gbuf[0];
#pragma unroll
    for (int r = 0; r < 4; ++r) {
      int g = gbuf[r];
      if (g != cur) {
        if (cur >= 0) atomicAdd(&gsum[cur * 64 + lane], s);
        s = 0.0f;
        cur = g;
      }
      if (g >= 0) s += obuf[r][lane];
    }
    if (cur >= 0) atomicAdd(&gsum[cur * 64 + lane], s);
  }
}

// ---- output: mean via binary search on sorted batch ---------------------

__device__ __forceinline__ int lbound(const int* __restrict__ a, int n, int v) {
  int lo = 0, hi = n;
  while (lo < hi) {
    int mid = (lo + hi) >> 1;
    if (a[mid] < v) lo = mid + 1; else hi = mid;
  }
  return lo;
}

__global__ void out_kernel(const float* __restrict__ gsum, const int* __restrict__ batch,
                           int N, float* __restrict__ out) {
  int t = blockIdx.x * blockDim.x + threadIdx.x;
  if (t >= NG * 64) return;
  int g = t >> 6;
  int cnt = lbound(batch, N, g + 1) - lbound(batch, N, g);
  out[t] = gsum[t] / fmaxf((float)cnt, 1.0f);
}

// ---- launch --------------------------------------------------------------

extern "C" void kernel_launch(void* const* d_in, const int* in_sizes, int n_in,
                              void* d_out, int out_size, void* d_ws, size_t ws_size,
                              hipStream_t stream) {
  const float* x = (const float*)d_in[0];
  const int* ei = (const int*)d_in[1];     // [2,E]: src row then dst row
  const int* batch = (const int*)d_in[2];  // sorted graph ids
  const float* W1 = (const float*)d_in[4];
  const float* b1 = (const float*)d_in[5];
  const float* W2 = (const float*)d_in[6];
  const float* b2 = (const float*)d_in[7];

  const int N = in_sizes[0] / 4;
  const int E = in_sizes[1] / 2;
  const int K = (N + 255) >> 8;                 // buckets (dst>>8)
  const int nblkE = (E + CHUNK - 1) / CHUNK;    // edge chunks
  const int M2 = K * nblkE;
  const int NB2 = (M2 + 255) / 256;             // <= 1024

  // ws layout (4B units unless noted):
  // [gsum 64*NG] <- zeroed each call
  // [deg N][rowptr N][xs 4N][dis N][h1p 64N halves][off M2][bsum2 1024]
  // [psrc E][pld E ushorts][esrc E]
  float* gsum = (float*)d_ws;
  int* deg = (int*)(gsum + 64 * NG);
  int* rowptr = deg + N;
  float* xs = (float*)(rowptr + N);             // 16B aligned (N%4==0)
  float* dis = xs + (long)4 * N;
  __half* h1p = (__half*)(dis + N);
  int* off = (int*)(dis + N + (long)32 * N);
  int* bsum2 = off + M2;
  int* psrc = bsum2 + 1024;
  unsigned short* pld = (unsigned short*)(psrc + E);
  int* esrc = (int*)(pld + E);                  // E even -> 4B aligned

  hipMemsetAsync(d_ws, 0, (size_t)64 * NG * 4, stream);

  const int B = 256;
  hist_kernel<<<nblkE, 256, 0, stream>>>(ei, E, nblkE, K, off);
  bsum_kernel<<<NB2, 256, 0, stream>>>(off, bsum2, M2);
  bscan_kernel<<<1, 1024, 0, stream>>>(bsum2, NB2);
  offadd_kernel<<<NB2, 256, 0, stream>>>(off, bsum2, M2);
  part_kernel<<<nblkE, 256, 0, stream>>>(ei, E, nblkE, K, off, psrc, pld);
  csr2_kernel<<<K, 256, 0, stream>>>(off, nblkE, K, psrc, pld, x, deg, rowptr, dis, xs, esrc, N, E);
  l1_kernel<<<(N + 3) / 4, 256, 0, stream>>>(rowptr, deg, esrc, xs, x, dis, W1, b1, h1p, N);
  l2_kernel<<<(N + 3) / 4, 256, 0, stream>>>(rowptr, deg, esrc, h1p, dis, W2, b2, batch, gsum, N);
  out_kernel<<<(NG * 64 + B - 1) / B, B, 0, stream>>>(gsum, batch, N, (float*)d_out);
}